// Round 11
// baseline (51.146 us; speedup 1.0000x reference)
//
#include <hip/hip_runtime.h>

#define NB 32      // batch
#define NT 2048    // frames
#define ND 1024    // feature dim
#define NS 128     // max segments
#define CH 128     // frames per chunk
#define NQ (NT / CH)  // 16 chunks per batch row

typedef float f32x4 __attribute__((ext_vector_type(4)));  // clang-native vec4

__device__ __forceinline__ void nt_store4(float* p, float a, float b, float c, float d) {
    f32x4 v = {a, b, c, d};
    __builtin_nontemporal_store(v, (f32x4*)p);
}

// ---------------------------------------------------------------------------
// Fused kernel: per-block boundary scan (8 KB, L2-broadcast) + chunk pooling
// with two-group register double-buffering (8-16 loads in flight per wave).
// CH=128: halves partial traffic vs CH=64, more sole-owner final writes.
// grid = (NQ, NB) = 512 blocks, 256 threads, 2 blocks/CU.
// ---------------------------------------------------------------------------
__global__ __launch_bounds__(256, 4)
void fused_pool_kernel(const float* __restrict__ x,           // [NB, NT, ND]
                       const int* __restrict__ in_boundary,   // [NB, NT+1]
                       int* __restrict__ seg_start_ws,        // [NB, NS]
                       int* __restrict__ seg_count_ws,        // [NB, NS]
                       float* __restrict__ partial,           // [NB, NQ, 2, ND]
                       float* __restrict__ pooled,            // [NB, NS, ND]
                       float* __restrict__ out1,              // [NB, NS]
                       float* __restrict__ out2)              // [NB, NT+1]
{
    const int q    = blockIdx.x;
    const int b    = blockIdx.y;
    const int tid  = threadIdx.x;             // 256 threads = 4 waves
    const int lane = tid & 63;
    const int wid  = tid >> 6;
    const int t0   = q * CH;
    const int* bd  = in_boundary + (size_t)b * (NT + 1);

    const float4* xp = (const float4*)(x + (size_t)b * NT * ND) + tid;

#define LOADG(P, g)                                            \
    P##0 = xp[(size_t)(t0 + (g) * 8 + 0) * (ND / 4)];          \
    P##1 = xp[(size_t)(t0 + (g) * 8 + 1) * (ND / 4)];          \
    P##2 = xp[(size_t)(t0 + (g) * 8 + 2) * (ND / 4)];          \
    P##3 = xp[(size_t)(t0 + (g) * 8 + 3) * (ND / 4)];          \
    P##4 = xp[(size_t)(t0 + (g) * 8 + 4) * (ND / 4)];          \
    P##5 = xp[(size_t)(t0 + (g) * 8 + 5) * (ND / 4)];          \
    P##6 = xp[(size_t)(t0 + (g) * 8 + 6) * (ND / 4)];          \
    P##7 = xp[(size_t)(t0 + (g) * 8 + 7) * (ND / 4)]

#define CONSG(P, g)                                            \
    consume(t0 + (g) * 8 + 0, P##0);                           \
    consume(t0 + (g) * 8 + 1, P##1);                           \
    consume(t0 + (g) * 8 + 2, P##2);                           \
    consume(t0 + (g) * 8 + 3, P##3);                           \
    consume(t0 + (g) * 8 + 4, P##4);                           \
    consume(t0 + (g) * 8 + 5, P##5);                           \
    consume(t0 + (g) * 8 + 6, P##6);                           \
    consume(t0 + (g) * 8 + 7, P##7)

    float4 A0, A1, A2, A3, A4, A5, A6, A7;
    float4 B0, B1, B2, B3, B4, B5, B6, B7;

    // ---- issue group 0 loads; scan hides under their latency ----
    LOADG(A, 0);

    __shared__ int starts[NS + 1];
    __shared__ int wtot[4];
    __shared__ int sid_all[NT];

    for (int s = tid; s <= NS; s += 256) starts[s] = NT;  // default: no segment

    // ---- full-row boundary scan (thread tid owns frames tid*8..tid*8+7) ----
    const int f0 = tid * 8;
    int bv[8];
    int local = 0;
#pragma unroll
    for (int j = 0; j < 8; ++j) {
        int t = f0 + j;
        int bit = (t == 0) ? 1 : bd[t];       // force boundary at frame 0
        bv[j] = bit;
        local += bit;
    }

    int incl = local;
#pragma unroll
    for (int off = 1; off < 64; off <<= 1) {
        int n = __shfl_up(incl, off, 64);
        if (lane >= off) incl += n;
    }
    if (lane == 63) wtot[wid] = incl;
    __syncthreads();

    int wpref = 0;
#pragma unroll
    for (int w = 0; w < 4; ++w)
        if (w < wid) wpref += wtot[w];
    const int excl = wpref + incl - local;

    int run = excl;
#pragma unroll
    for (int j = 0; j < 8; ++j) {
        run += bv[j];
        int seg = run - 1;
        sid_all[f0 + j] = seg;
        if (bv[j] && seg <= NS) starts[seg] = f0 + j;
    }
    __syncthreads();

    // ---- pooling over my chunk, double-buffered ----
    const int s_first = sid_all[t0];
    float4 acc = make_float4(0.f, 0.f, 0.f, 0.f);
    int cur = s_first;

    auto flush = [&](int seg, const float4& a) {
        if (seg >= NS) return;
        const int st = starts[seg];
        const int c  = starts[seg + 1] - st;
        if (st >= t0 && st + c <= t0 + CH) {
            const float inv = 1.0f / (float)c;
            nt_store4(pooled + ((size_t)b * NS + seg) * ND + tid * 4,
                      a.x * inv, a.y * inv, a.z * inv, a.w * inv);
        } else {
            const int slot = (seg == s_first) ? 0 : 1;
            ((float4*)partial)[(((size_t)b * NQ + q) * 2 + slot) * (ND / 4) + tid] = a;
        }
    };

    auto consume = [&](int t, const float4& v) {
        int sg = sid_all[t];                  // LDS broadcast, uniform
        if (sg != cur) {
            flush(cur, acc);
            acc = make_float4(0.f, 0.f, 0.f, 0.f);
            cur = sg;
        }
        acc.x += v.x; acc.y += v.y; acc.z += v.z; acc.w += v.w;
    };

    LOADG(B, 1);  CONSG(A, 0);                // next group in flight while consuming
    LOADG(A, 2);  CONSG(B, 1);
    LOADG(B, 3);  CONSG(A, 2);
    LOADG(A, 4);  CONSG(B, 3);
    LOADG(B, 5);  CONSG(A, 4);
    LOADG(A, 6);  CONSG(B, 5);
    LOADG(B, 7);  CONSG(A, 6);
    LOADG(A, 8);  CONSG(B, 7);
    LOADG(B, 9);  CONSG(A, 8);
    LOADG(A, 10); CONSG(B, 9);
    LOADG(B, 11); CONSG(A, 10);
    LOADG(A, 12); CONSG(B, 11);
    LOADG(B, 13); CONSG(A, 12);
    LOADG(A, 14); CONSG(B, 13);
    LOADG(B, 15); CONSG(A, 14);
    CONSG(B, 15);
    flush(cur, acc);
#undef LOADG
#undef CONSG

    // ---- q==0 blocks emit scalar outputs + ws tables for combine ----
    if (q == 0) {
        if (tid < NS) {
            int st = starts[tid];
            int c  = starts[tid + 1] - st;
            seg_start_ws[b * NS + tid] = st;
            seg_count_ws[b * NS + tid] = c;
            out1[b * NS + tid] = (c > 0) ? 1.0f : 0.0f;
        }
        for (int t = tid; t <= NT; t += 256)
            out2[(size_t)b * (NT + 1) + t] = (float)bd[t];
    }
}

// ---------------------------------------------------------------------------
// Kernel C: combine crossing-segment partials; zero empty rows.
// grid = (NS, NB), 256 threads.
// ---------------------------------------------------------------------------
__global__ __launch_bounds__(256)
void combine_kernel(const int* __restrict__ seg_start,    // [NB, NS]
                    const int* __restrict__ seg_count,    // [NB, NS]
                    const float* __restrict__ partial,    // [NB, NQ, 2, ND]
                    float* __restrict__ pooled)           // [NB, NS, ND]
{
    const int s   = blockIdx.x;
    const int b   = blockIdx.y;
    const int tid = threadIdx.x;

    const int st = seg_start[b * NS + s];
    const int c  = seg_count[b * NS + s];
    float* out = pooled + ((size_t)b * NS + s) * ND + tid * 4;

    if (c <= 0) {                             // empty segment: zero the row
        nt_store4(out, 0.f, 0.f, 0.f, 0.f);
        return;
    }
    const int q0 = st / CH;
    const int q1 = (st + c - 1) / CH;
    if (q0 == q1) return;                     // written by its chunk already

    const float4* pp = (const float4*)partial + tid;
    const int slot0 = (st == q0 * CH) ? 0 : 1;
    float4 a = pp[(((size_t)b * NQ + q0) * 2 + slot0) * (ND / 4)];
    for (int q = q0 + 1; q <= q1; ++q) {
        float4 v = pp[(((size_t)b * NQ + q) * 2 + 0) * (ND / 4)];
        a.x += v.x; a.y += v.y; a.z += v.z; a.w += v.w;
    }
    const float inv = 1.0f / (float)c;
    nt_store4(out, a.x * inv, a.y * inv, a.z * inv, a.w * inv);
}

// ---------------------------------------------------------------------------
extern "C" void kernel_launch(void* const* d_in, const int* in_sizes, int n_in,
                              void* d_out, int out_size, void* d_ws, size_t ws_size,
                              hipStream_t stream) {
    const float* x           = (const float*)d_in[0];       // [NB, NT, ND]
    const int*   in_boundary = (const int*)d_in[1];         // [NB, NT+1]

    float* pooled = (float*)d_out;                          // [NB, NS, ND]
    float* out1   = pooled + (size_t)NB * NS * ND;          // [NB, NS]
    float* out2   = out1 + (size_t)NB * NS;                 // [NB, NT+1]

    int*   seg_start = (int*)d_ws;                          // [NB, NS]
    int*   seg_count = seg_start + NB * NS;                 // [NB, NS]
    float* partial   = (float*)(seg_count + NB * NS);       // [NB, NQ, 2, ND]

    fused_pool_kernel<<<dim3(NQ, NB), 256, 0, stream>>>(
        x, in_boundary, seg_start, seg_count, partial, pooled, out1, out2);
    combine_kernel<<<dim3(NS, NB), 256, 0, stream>>>(seg_start, seg_count,
                                                     partial, pooled);
}